// Round 1
// baseline (519.989 us; speedup 1.0000x reference)
//
#include <hip/hip_runtime.h>

#define N_NODES 100000
#define N_EDGES 1600000
#define D 64
#define N_LAYERS 5
#define SCAN_BLOCKS 391   // ceil(N_NODES / 256)

typedef unsigned short u16;
typedef __attribute__((ext_vector_type(8))) short bf16x8;
typedef __attribute__((ext_vector_type(4))) float f32x4;

__device__ __forceinline__ float bf2f(u16 u) {
    union { unsigned int i; float f; } v;
    v.i = ((unsigned int)u) << 16;
    return v.f;
}
__device__ __forceinline__ u16 f2bf(float f) {
    union { float f; unsigned int i; } v;
    v.f = f;
    unsigned int r = v.i + 0x7FFFu + ((v.i >> 16) & 1u);  // round-nearest-even
    return (u16)(r >> 16);
}
__device__ __forceinline__ float bf2f_lo(unsigned int pk) {
    union { unsigned int i; float f; } v;
    v.i = pk << 16;
    return v.f;
}
__device__ __forceinline__ float bf2f_hi(unsigned int pk) {
    union { unsigned int i; float f; } v;
    v.i = pk & 0xFFFF0000u;
    return v.f;
}

// ============================ CSR build (once per launch) ====================
// hist also captures each edge's occurrence index k[e] among edges sharing its
// dst (unique in [0, deg)). place then derives its slot as rowptr[d]+k[e] with
// NO atomic and no atomic->store dependence. dst read is non-temporal: pure
// streaming, keep L2 for the counts array.

__global__ __launch_bounds__(256) void hist_kernel(
    const int* __restrict__ dst, int* __restrict__ counts,
    int* __restrict__ kidx)
{
    int e = blockIdx.x * 256 + threadIdx.x;
    if (e < N_EDGES) {
        int d = __builtin_nontemporal_load(&dst[e]);
        int k = atomicAdd(&counts[d], 1);
        __builtin_nontemporal_store(k, &kidx[e]);
    }
}

__global__ __launch_bounds__(256) void scan_bsum_kernel(
    const int* __restrict__ counts, int* __restrict__ bsum)
{
    __shared__ int red[256];
    int t = threadIdx.x;
    int i = blockIdx.x * 256 + t;
    red[t] = (i < N_NODES) ? counts[i] : 0;
    __syncthreads();
    for (int off = 128; off > 0; off >>= 1) {
        if (t < off) red[t] += red[t + off];
        __syncthreads();
    }
    if (t == 0) bsum[blockIdx.x] = red[0];
}

__global__ __launch_bounds__(512) void scan_bscan_kernel(
    const int* __restrict__ bsum, int* __restrict__ bscan,
    int* __restrict__ rowptr)
{
    __shared__ int s[512];
    int t = threadIdx.x;
    int v = (t < SCAN_BLOCKS) ? bsum[t] : 0;
    s[t] = v;
    __syncthreads();
    for (int off = 1; off < 512; off <<= 1) {
        int u = (t >= off) ? s[t - off] : 0;
        __syncthreads();
        s[t] += u;
        __syncthreads();
    }
    if (t < SCAN_BLOCKS) bscan[t] = s[t] - v;
    if (t == 511) rowptr[N_NODES] = s[511];
}

__global__ __launch_bounds__(256) void scan_final_kernel(
    const int* __restrict__ counts, const int* __restrict__ bscan,
    int* __restrict__ rowptr)
{
    __shared__ int s[256];
    int t = threadIdx.x;
    int i = blockIdx.x * 256 + t;
    int v = (i < N_NODES) ? counts[i] : 0;
    s[t] = v;
    __syncthreads();
    for (int off = 1; off < 256; off <<= 1) {
        int u = (t >= off) ? s[t - off] : 0;
        __syncthreads();
        s[t] += u;
        __syncthreads();
    }
    if (i < N_NODES) rowptr[i] = s[t] - v + bscan[blockIdx.x];
}

// ============ Placement, XCD-partitioned for write-sector locality ===========
// Node space split into 8 regions of 12500; block (blockIdx%8 == x) handles
// only dst in region x, so all stores to a given edges[] sector come from ONE
// XCD and can merge in its L2. The reads (dst 8x, src/ew/k 1x scattered) are
// pure streaming with ZERO intra-pass reuse — they are non-temporal so they
// don't evict the region's 1.6 MB of partially-filled write lines (a node's
// 8-edge sector accumulates stores over the WHOLE kernel; any L2 thrash turns
// each 8B store into a 64B partial-sector writeback — measured 94.7 MB vs
// 12.8 MB ideal before this change). rowptr[d] stays cached (50 KB region
// slice, reused ~16x). Slot = rowptr[d] + k[e]: no atomics here.
__global__ __launch_bounds__(256) void place_kernel(
    const int* __restrict__ src, const int* __restrict__ dst,
    const float* __restrict__ ew, const int* __restrict__ kidx,
    const int* __restrict__ rowptr, int2* __restrict__ edges)
{
    const int x  = blockIdx.x & 7;    // region / intended XCD
    const int ci = blockIdx.x >> 3;   // edge chunk
    const int xlo = x * 12500, xhi = xlo + 12500;   // 100000 = 8 * 12500
    const int e0 = ci * 12500;                      // 1.6M = 128 * 12500
    const int e1 = e0 + 12500;
    for (int e = e0 + threadIdx.x; e < e1; e += 256) {
        int d = __builtin_nontemporal_load(&dst[e]);
        if (d >= xlo && d < xhi) {
            int s   = __builtin_nontemporal_load(&src[e]);
            float w = __builtin_nontemporal_load(&ew[e]);
            int k   = __builtin_nontemporal_load(&kidx[e]);
            int p = rowptr[d] + k;
            edges[p] = make_int2(s, __float_as_int(w));
        }
    }
}

// ======================= f32 -> bf16 convert (input x) =======================
__global__ __launch_bounds__(256) void f2bf_kernel(
    const float* __restrict__ in, u16* __restrict__ out)
{
    int i = blockIdx.x * 256 + threadIdx.x;   // one float4 per thread
    if (i >= (N_NODES * D) / 4) return;
    float4 v = ((const float4*)in)[i];
    ushort4 o;
    o.x = f2bf(v.x); o.y = f2bf(v.y); o.z = f2bf(v.z); o.w = f2bf(v.w);
    ((ushort4*)out)[i] = o;
}

// ================== Weight prep: W2T[l][n][k] bf16, k = [Wrel;Wroot] =========
__global__ __launch_bounds__(256) void wprep_kernel(
    const float* __restrict__ Wrel, const float* __restrict__ Wroot,
    u16* __restrict__ W2T)
{
    int i = blockIdx.x * 256 + threadIdx.x;  // over 5*64*128
    if (i >= N_LAYERS * 64 * 128) return;
    int l = i / (64 * 128);
    int rem = i % (64 * 128);
    int n = rem >> 7;   // out dim
    int k = rem & 127;  // input dim (0..63 = rel/agg, 64..127 = root/x)
    float v = (k < 64) ? Wrel[l * 4096 + k * 64 + n]
                       : Wroot[l * 4096 + (k - 64) * 64 + n];
    W2T[i] = f2bf(v);
}

// ========== Aggregation: 2 nodes per wave, bf16x2 dword gather ===============
// Lanes 0-31 serve node (2*wid), lanes 32-63 node (2*wid+1). Each lane loads
// a packed bf16x2 dword (dims 2sl, 2sl+1), so ONE load instruction fetches two
// full 128B rows (256B). Halves are fully independent: own edge list, own
// trip count (exec-mask divergence only), width-32 shuffles, no butterfly.
__global__ __launch_bounds__(256) void agg_kernel(
    const u16* __restrict__ h, const int* __restrict__ rowptr,
    const int2* __restrict__ edges, u16* __restrict__ agg)
{
    int wid  = (blockIdx.x * 256 + threadIdx.x) >> 6;
    int lane = threadIdx.x & 63;
    int sl   = lane & 31;           // sublane: dim pair -> dims 2sl, 2sl+1
    int node = wid * 2 + (lane >> 5);
    if (node >= N_NODES) return;
    int b = rowptr[node];
    int e = rowptr[node + 1];
    float acc0 = 0.f, acc1 = 0.f;
    for (int base = b; base < e; base += 32) {
        int cnt = min(32, e - base);
        int idx = 0;
        float wv = 0.f;
        if (sl < cnt) {
            int2 p = edges[base + sl];   // per-half coalesced 256B segment
            idx = p.x;
            wv = __int_as_float(p.y);
        }
        int j = 0;
        for (; j + 8 <= cnt; j += 8) {
            int s0 = __shfl(idx, j + 0, 32), s1 = __shfl(idx, j + 1, 32);
            int s2 = __shfl(idx, j + 2, 32), s3 = __shfl(idx, j + 3, 32);
            int s4 = __shfl(idx, j + 4, 32), s5 = __shfl(idx, j + 5, 32);
            int s6 = __shfl(idx, j + 6, 32), s7 = __shfl(idx, j + 7, 32);
            float w0 = __shfl(wv, j + 0, 32), w1 = __shfl(wv, j + 1, 32);
            float w2 = __shfl(wv, j + 2, 32), w3 = __shfl(wv, j + 3, 32);
            float w4 = __shfl(wv, j + 4, 32), w5 = __shfl(wv, j + 5, 32);
            float w6 = __shfl(wv, j + 6, 32), w7 = __shfl(wv, j + 7, 32);
            unsigned int p0 = *(const unsigned int*)(h + ((size_t)s0 << 6) + sl * 2);
            unsigned int p1 = *(const unsigned int*)(h + ((size_t)s1 << 6) + sl * 2);
            unsigned int p2 = *(const unsigned int*)(h + ((size_t)s2 << 6) + sl * 2);
            unsigned int p3 = *(const unsigned int*)(h + ((size_t)s3 << 6) + sl * 2);
            unsigned int p4 = *(const unsigned int*)(h + ((size_t)s4 << 6) + sl * 2);
            unsigned int p5 = *(const unsigned int*)(h + ((size_t)s5 << 6) + sl * 2);
            unsigned int p6 = *(const unsigned int*)(h + ((size_t)s6 << 6) + sl * 2);
            unsigned int p7 = *(const unsigned int*)(h + ((size_t)s7 << 6) + sl * 2);
            acc0 += bf2f_lo(p0) * w0 + bf2f_lo(p1) * w1
                  + bf2f_lo(p2) * w2 + bf2f_lo(p3) * w3
                  + bf2f_lo(p4) * w4 + bf2f_lo(p5) * w5
                  + bf2f_lo(p6) * w6 + bf2f_lo(p7) * w7;
            acc1 += bf2f_hi(p0) * w0 + bf2f_hi(p1) * w1
                  + bf2f_hi(p2) * w2 + bf2f_hi(p3) * w3
                  + bf2f_hi(p4) * w4 + bf2f_hi(p5) * w5
                  + bf2f_hi(p6) * w6 + bf2f_hi(p7) * w7;
        }
        for (; j < cnt; ++j) {
            int s = __shfl(idx, j, 32);
            float w = __shfl(wv, j, 32);
            unsigned int pk = *(const unsigned int*)(h + ((size_t)s << 6) + sl * 2);
            acc0 += bf2f_lo(pk) * w;
            acc1 += bf2f_hi(pk) * w;
        }
    }
    unsigned int o = ((unsigned int)f2bf(acc1) << 16) | f2bf(acc0);
    *(unsigned int*)(agg + ((size_t)node << 6) + sl * 2) = o;
}

// =================== Dense update via MFMA (no LDS, no barrier) ==============
// Wave = 16 nodes x 64 out-dims = 4 n-tiles x 4 k-steps of 16x16x32 bf16.
// A-frag: lane holds AX[m=lane&15][k=quad*8+j] (doc-verified). B-frag:
// lane holds W2[k=quad*8+j][n=lane&15], read from transposed W2T[n][k].
// D: col(n)=lane&15, row(m)=quad*4+reg (doc-verified). In-place safe:
// wave reads/writes only its own 16 rows; stores data-depend on all loads.
__global__ __launch_bounds__(256) void update_mfma_kernel(
    const u16* __restrict__ hin, const u16* __restrict__ agg,
    const u16* __restrict__ W2T, const float* __restrict__ brel,
    u16* __restrict__ hout_bf, float* __restrict__ hout_f32, int relu)
{
    const int wave = threadIdx.x >> 6;
    const int lane = threadIdx.x & 63;
    const int nb16 = blockIdx.x * 64 + wave * 16;
    const int m = lane & 15;   // node-in-tile for A; out-dim-in-tile for B/D
    const int q = lane >> 4;   // quad

    int anode = nb16 + m;
    size_t rowa = (size_t)((anode < N_NODES) ? anode : 0) << 6;

    bf16x8 a[4];
    a[0] = *(const bf16x8*)(agg + rowa + q * 8);        // k  0..31
    a[1] = *(const bf16x8*)(agg + rowa + 32 + q * 8);   // k 32..63
    a[2] = *(const bf16x8*)(hin + rowa + q * 8);        // k 64..95
    a[3] = *(const bf16x8*)(hin + rowa + 32 + q * 8);   // k 96..127

    bf16x8 bfr[4][4];  // [ntile][kstep]
    #pragma unroll
    for (int nt = 0; nt < 4; ++nt)
        #pragma unroll
        for (int kk = 0; kk < 4; ++kk)
            bfr[nt][kk] = *(const bf16x8*)(W2T + (size_t)(nt * 16 + m) * 128
                                           + kk * 32 + q * 8);

    f32x4 acc[4];
    #pragma unroll
    for (int nt = 0; nt < 4; ++nt) {
        float bv = brel[nt * 16 + m];
        acc[nt] = (f32x4){bv, bv, bv, bv};
    }

    #pragma unroll
    for (int kk = 0; kk < 4; ++kk)
        #pragma unroll
        for (int nt = 0; nt < 4; ++nt)
            acc[nt] = __builtin_amdgcn_mfma_f32_16x16x32_bf16(
                a[kk], bfr[nt][kk], acc[nt], 0, 0, 0);

    #pragma unroll
    for (int nt = 0; nt < 4; ++nt)
        #pragma unroll
        for (int r = 0; r < 4; ++r) {
            int n2 = nb16 + q * 4 + r;           // node (row of D)
            if (n2 < N_NODES) {
                float v = acc[nt][r];
                if (relu) v = fmaxf(v, 0.f);
                int dim = nt * 16 + m;           // out dim (col of D)
                if (hout_f32) hout_f32[(size_t)n2 * 64 + dim] = v;
                else          hout_bf [(size_t)n2 * 64 + dim] = f2bf(v);
            }
        }
}

extern "C" void kernel_launch(void* const* d_in, const int* in_sizes, int n_in,
                              void* d_out, int out_size, void* d_ws, size_t ws_size,
                              hipStream_t stream)
{
    const float* x     = (const float*)d_in[0];
    const int*   ei    = (const int*)d_in[1];   // [2, E] int32
    const float* ew    = (const float*)d_in[2];
    const float* Wrel  = (const float*)d_in[3]; // [5, 64, 64]
    const float* brel  = (const float*)d_in[4]; // [5, 64]
    const float* Wroot = (const float*)d_in[5]; // [5, 64, 64]
    float* out = (float*)d_out;

    const int* src = ei;
    const int* dst = ei + N_EDGES;

    const size_t featb_bytes = (size_t)N_NODES * D * 2;  // 12.8 MB bf16
    char* ws = (char*)d_ws;
    size_t off = 0;
    u16*  hb     = (u16*)(ws + off);  off += featb_bytes;
    u16*  aggb   = (u16*)(ws + off);  off += featb_bytes;
    u16*  W2T    = (u16*)(ws + off);  off += (size_t)N_LAYERS * 64 * 128 * 2;
    int*  counts = (int*)(ws + off);  off += 400000;
    int*  rowptr = (int*)(ws + off);  off += 400016;
    int*  bsum   = (int*)(ws + off);  off += 2048;
    int*  bscan  = (int*)(ws + off);  off += 2048;
    int2* edges  = (int2*)(ws + off); off += (size_t)N_EDGES * 8;

    // kidx aliases aggb: only live during CSR build (hist -> place), which
    // completes (stream-ordered) before the first agg_kernel writes aggb.
    int* kidx = (int*)aggb;

    const int eblocks = (N_EDGES + 255) / 256;       // 6250
    const int pblocks = 8 * 128;                     // 8 regions x 128 chunks
    const int cblocks = (N_NODES * D / 4 + 255) / 256;
    const int wblocks = (N_LAYERS * 64 * 128 + 255) / 256;  // 160
    const int ablocks = ((N_NODES + 1) / 2 + 3) / 4; // 12500 (2 nodes/wave)
    const int ublocks = (N_NODES + 63) / 64;         // 1563

    // ---- CSR build + converts ----
    hipMemsetAsync(counts, 0, N_NODES * sizeof(int), stream);
    hist_kernel<<<eblocks, 256, 0, stream>>>(dst, counts, kidx);
    scan_bsum_kernel<<<SCAN_BLOCKS, 256, 0, stream>>>(counts, bsum);
    scan_bscan_kernel<<<1, 512, 0, stream>>>(bsum, bscan, rowptr);
    scan_final_kernel<<<SCAN_BLOCKS, 256, 0, stream>>>(counts, bscan, rowptr);
    place_kernel<<<pblocks, 256, 0, stream>>>(src, dst, ew, kidx, rowptr, edges);
    f2bf_kernel<<<cblocks, 256, 0, stream>>>(x, hb);
    wprep_kernel<<<wblocks, 256, 0, stream>>>(Wrel, Wroot, W2T);

    // ---- 5 GraphConv layers (hb updated in place; wave-local rows) ----
    for (int layer = 0; layer < N_LAYERS; ++layer) {
        agg_kernel<<<ablocks, 256, 0, stream>>>(hb, rowptr, edges, aggb);
        int last = (layer == N_LAYERS - 1);
        update_mfma_kernel<<<ublocks, 256, 0, stream>>>(
            hb, aggb, W2T + (size_t)layer * 64 * 128,
            brel + (size_t)layer * D,
            last ? nullptr : hb, last ? out : nullptr,
            last ? 0 : 1);
    }
}

// Round 2
// 502.437 us; speedup vs baseline: 1.0349x; 1.0349x over previous
//
#include <hip/hip_runtime.h>

#define N_NODES 100000
#define N_EDGES 1600000
#define D 64
#define N_LAYERS 5
#define SCAN_BLOCKS 391   // ceil(N_NODES / 256)
#define ABLK 2000         // edges per bin_kernel block -> 800 blocks exactly
#define NREG 12500        // nodes per region (100000 / 8)
#define SC_NC 96          // scatter chunks per region

typedef unsigned short u16;
typedef __attribute__((ext_vector_type(8))) short bf16x8;
typedef __attribute__((ext_vector_type(4))) float f32x4;

__device__ __forceinline__ float bf2f(u16 u) {
    union { unsigned int i; float f; } v;
    v.i = ((unsigned int)u) << 16;
    return v.f;
}
__device__ __forceinline__ u16 f2bf(float f) {
    union { float f; unsigned int i; } v;
    v.f = f;
    unsigned int r = v.i + 0x7FFFu + ((v.i >> 16) & 1u);  // round-nearest-even
    return (u16)(r >> 16);
}
__device__ __forceinline__ float bf2f_lo(unsigned int pk) {
    union { unsigned int i; float f; } v;
    v.i = pk << 16;
    return v.f;
}
__device__ __forceinline__ float bf2f_hi(unsigned int pk) {
    union { unsigned int i; float f; } v;
    v.i = pk & 0xFFFF0000u;
    return v.f;
}

// ============================ CSR build (once per launch) ====================
// hist captures each edge's occurrence index k[e] among edges sharing its dst
// (unique in [0, deg)). Final slot = rowptr[d] + k[e] -> placement needs no
// atomics and no atomic->store dependence.

__global__ __launch_bounds__(256) void hist_kernel(
    const int* __restrict__ dst, int* __restrict__ counts,
    int* __restrict__ kidx)
{
    int e = blockIdx.x * 256 + threadIdx.x;
    if (e < N_EDGES) {
        int d = __builtin_nontemporal_load(&dst[e]);
        int k = atomicAdd(&counts[d], 1);
        __builtin_nontemporal_store(k, &kidx[e]);
    }
}

__global__ __launch_bounds__(256) void scan_bsum_kernel(
    const int* __restrict__ counts, int* __restrict__ bsum)
{
    __shared__ int red[256];
    int t = threadIdx.x;
    int i = blockIdx.x * 256 + t;
    red[t] = (i < N_NODES) ? counts[i] : 0;
    __syncthreads();
    for (int off = 128; off > 0; off >>= 1) {
        if (t < off) red[t] += red[t + off];
        __syncthreads();
    }
    if (t == 0) bsum[blockIdx.x] = red[0];
}

__global__ __launch_bounds__(512) void scan_bscan_kernel(
    const int* __restrict__ bsum, int* __restrict__ bscan,
    int* __restrict__ rowptr)
{
    __shared__ int s[512];
    int t = threadIdx.x;
    int v = (t < SCAN_BLOCKS) ? bsum[t] : 0;
    s[t] = v;
    __syncthreads();
    for (int off = 1; off < 512; off <<= 1) {
        int u = (t >= off) ? s[t - off] : 0;
        __syncthreads();
        s[t] += u;
        __syncthreads();
    }
    if (t < SCAN_BLOCKS) bscan[t] = s[t] - v;
    if (t == 511) rowptr[N_NODES] = s[511];
}

__global__ __launch_bounds__(256) void scan_final_kernel(
    const int* __restrict__ counts, const int* __restrict__ bscan,
    int* __restrict__ rowptr)
{
    __shared__ int s[256];
    int t = threadIdx.x;
    int i = blockIdx.x * 256 + t;
    int v = (i < N_NODES) ? counts[i] : 0;
    s[t] = v;
    __syncthreads();
    for (int off = 1; off < 256; off <<= 1) {
        int u = (t >= off) ? s[t - off] : 0;
        __syncthreads();
        s[t] += u;
        __syncthreads();
    }
    if (i < N_NODES) rowptr[i] = s[t] - v + bscan[blockIdx.x];
}

// rcur[r] = start of region r's record segment = rowptr[r*NREG]. Region
// segment sizes come free from rowptr (regions are contiguous node ranges).
__global__ void init_rcur_kernel(const int* __restrict__ rowptr,
                                 int* __restrict__ rcur)
{
    int t = threadIdx.x;
    if (t < 8) rcur[t] = rowptr[t * NREG];
}

// ================= Phase A: bin edge records by dst region ===================
// Replaces the old 8-pass place_kernel whose predicated 1/8-density loads
// re-fetched every 64B line of every per-edge array in every pass (measured
// 105.9 MB FETCH vs ~27 MB unique). Here every array is read exactly ONCE,
// coalesced. Records {p, src, ew} go to region-partitioned segments so the
// scatter pass reads contiguously. Two in-block passes over dst (2nd hits L1:
// 8KB/block); one global atomicAdd per (block, region) -> reservations are
// ~1KB contiguous per array, so cross-block 64B-line sharing is ~6%.
__global__ __launch_bounds__(256) void bin_kernel(
    const int* __restrict__ src, const int* __restrict__ dst,
    const float* __restrict__ ew, const int* __restrict__ kidx,
    const int* __restrict__ rowptr, int* __restrict__ rcur,
    int* __restrict__ prec, int* __restrict__ srec, float* __restrict__ wrec)
{
    __shared__ int cnt[8];
    __shared__ int cur[8];
    const int e0 = blockIdx.x * ABLK;
    if (threadIdx.x < 8) cnt[threadIdx.x] = 0;
    __syncthreads();
    for (int e = e0 + threadIdx.x; e < e0 + ABLK; e += 256) {
        int d = dst[e];                    // plain: want L1 hit in pass 2
        atomicAdd(&cnt[d / NREG], 1);
    }
    __syncthreads();
    if (threadIdx.x < 8)
        cur[threadIdx.x] = atomicAdd(&rcur[threadIdx.x], cnt[threadIdx.x]);
    __syncthreads();
    for (int e = e0 + threadIdx.x; e < e0 + ABLK; e += 256) {
        int d = dst[e];                    // L1-resident re-read
        int r = d / NREG;
        int pos = atomicAdd(&cur[r], 1);   // LDS rank
        int p = rowptr[d] + __builtin_nontemporal_load(&kidx[e]);
        prec[pos] = p;
        srec[pos] = __builtin_nontemporal_load(&src[e]);
        wrec[pos] = __builtin_nontemporal_load(&ew[e]);
    }
}

// ================= Phase B: region-local scatter into CSR ====================
// Block (blockIdx&7 == r) reads region r's record segment sequentially (nt:
// zero reuse, keep L2 for the write working set) and scatters edges[p] within
// region r's 1.6MB slice. With gfx950's round-robin blockIdx->XCD dispatch all
// stores to a given edges[] sector come from ONE XCD -> its L2 merges the ~8
// edges/sector before writeback (round-1 verified: WRITE 94.7 -> 24.4 MB).
__global__ __launch_bounds__(256) void scatter_kernel(
    const int* __restrict__ prec, const int* __restrict__ srec,
    const float* __restrict__ wrec, const int* __restrict__ rowptr,
    int2* __restrict__ edges)
{
    const int x  = blockIdx.x & 7;    // region / intended XCD
    const int ci = blockIdx.x >> 3;   // chunk within region
    const int lo = rowptr[x * NREG];
    const int hi = rowptr[(x + 1) * NREG];
    const int n  = hi - lo;
    const int per = (n + SC_NC - 1) / SC_NC;
    const int b = lo + ci * per;
    const int t = min(b + per, hi);
    for (int i = b + threadIdx.x; i < t; i += 256) {
        int p   = __builtin_nontemporal_load(&prec[i]);
        int s   = __builtin_nontemporal_load(&srec[i]);
        float w = __builtin_nontemporal_load(&wrec[i]);
        edges[p] = make_int2(s, __float_as_int(w));
    }
}

// ======================= f32 -> bf16 convert (input x) =======================
__global__ __launch_bounds__(256) void f2bf_kernel(
    const float* __restrict__ in, u16* __restrict__ out)
{
    int i = blockIdx.x * 256 + threadIdx.x;   // one float4 per thread
    if (i >= (N_NODES * D) / 4) return;
    float4 v = ((const float4*)in)[i];
    ushort4 o;
    o.x = f2bf(v.x); o.y = f2bf(v.y); o.z = f2bf(v.z); o.w = f2bf(v.w);
    ((ushort4*)out)[i] = o;
}

// ================== Weight prep: W2T[l][n][k] bf16, k = [Wrel;Wroot] =========
__global__ __launch_bounds__(256) void wprep_kernel(
    const float* __restrict__ Wrel, const float* __restrict__ Wroot,
    u16* __restrict__ W2T)
{
    int i = blockIdx.x * 256 + threadIdx.x;  // over 5*64*128
    if (i >= N_LAYERS * 64 * 128) return;
    int l = i / (64 * 128);
    int rem = i % (64 * 128);
    int n = rem >> 7;   // out dim
    int k = rem & 127;  // input dim (0..63 = rel/agg, 64..127 = root/x)
    float v = (k < 64) ? Wrel[l * 4096 + k * 64 + n]
                       : Wroot[l * 4096 + (k - 64) * 64 + n];
    W2T[i] = f2bf(v);
}

// ========== Aggregation: 2 nodes per wave, bf16x2 dword gather ===============
// Lanes 0-31 serve node (2*wid), lanes 32-63 node (2*wid+1). Each lane loads
// a packed bf16x2 dword (dims 2sl, 2sl+1), so ONE load instruction fetches two
// full 128B rows (256B). Halves are fully independent: own edge list, own
// trip count (exec-mask divergence only), width-32 shuffles, no butterfly.
__global__ __launch_bounds__(256) void agg_kernel(
    const u16* __restrict__ h, const int* __restrict__ rowptr,
    const int2* __restrict__ edges, u16* __restrict__ agg)
{
    int wid  = (blockIdx.x * 256 + threadIdx.x) >> 6;
    int lane = threadIdx.x & 63;
    int sl   = lane & 31;           // sublane: dim pair -> dims 2sl, 2sl+1
    int node = wid * 2 + (lane >> 5);
    if (node >= N_NODES) return;
    int b = rowptr[node];
    int e = rowptr[node + 1];
    float acc0 = 0.f, acc1 = 0.f;
    for (int base = b; base < e; base += 32) {
        int cnt = min(32, e - base);
        int idx = 0;
        float wv = 0.f;
        if (sl < cnt) {
            int2 p = edges[base + sl];   // per-half coalesced 256B segment
            idx = p.x;
            wv = __int_as_float(p.y);
        }
        int j = 0;
        for (; j + 8 <= cnt; j += 8) {
            int s0 = __shfl(idx, j + 0, 32), s1 = __shfl(idx, j + 1, 32);
            int s2 = __shfl(idx, j + 2, 32), s3 = __shfl(idx, j + 3, 32);
            int s4 = __shfl(idx, j + 4, 32), s5 = __shfl(idx, j + 5, 32);
            int s6 = __shfl(idx, j + 6, 32), s7 = __shfl(idx, j + 7, 32);
            float w0 = __shfl(wv, j + 0, 32), w1 = __shfl(wv, j + 1, 32);
            float w2 = __shfl(wv, j + 2, 32), w3 = __shfl(wv, j + 3, 32);
            float w4 = __shfl(wv, j + 4, 32), w5 = __shfl(wv, j + 5, 32);
            float w6 = __shfl(wv, j + 6, 32), w7 = __shfl(wv, j + 7, 32);
            unsigned int p0 = *(const unsigned int*)(h + ((size_t)s0 << 6) + sl * 2);
            unsigned int p1 = *(const unsigned int*)(h + ((size_t)s1 << 6) + sl * 2);
            unsigned int p2 = *(const unsigned int*)(h + ((size_t)s2 << 6) + sl * 2);
            unsigned int p3 = *(const unsigned int*)(h + ((size_t)s3 << 6) + sl * 2);
            unsigned int p4 = *(const unsigned int*)(h + ((size_t)s4 << 6) + sl * 2);
            unsigned int p5 = *(const unsigned int*)(h + ((size_t)s5 << 6) + sl * 2);
            unsigned int p6 = *(const unsigned int*)(h + ((size_t)s6 << 6) + sl * 2);
            unsigned int p7 = *(const unsigned int*)(h + ((size_t)s7 << 6) + sl * 2);
            acc0 += bf2f_lo(p0) * w0 + bf2f_lo(p1) * w1
                  + bf2f_lo(p2) * w2 + bf2f_lo(p3) * w3
                  + bf2f_lo(p4) * w4 + bf2f_lo(p5) * w5
                  + bf2f_lo(p6) * w6 + bf2f_lo(p7) * w7;
            acc1 += bf2f_hi(p0) * w0 + bf2f_hi(p1) * w1
                  + bf2f_hi(p2) * w2 + bf2f_hi(p3) * w3
                  + bf2f_hi(p4) * w4 + bf2f_hi(p5) * w5
                  + bf2f_hi(p6) * w6 + bf2f_hi(p7) * w7;
        }
        for (; j < cnt; ++j) {
            int s = __shfl(idx, j, 32);
            float w = __shfl(wv, j, 32);
            unsigned int pk = *(const unsigned int*)(h + ((size_t)s << 6) + sl * 2);
            acc0 += bf2f_lo(pk) * w;
            acc1 += bf2f_hi(pk) * w;
        }
    }
    unsigned int o = ((unsigned int)f2bf(acc1) << 16) | f2bf(acc0);
    *(unsigned int*)(agg + ((size_t)node << 6) + sl * 2) = o;
}

// =================== Dense update via MFMA (no LDS, no barrier) ==============
// Wave = 16 nodes x 64 out-dims = 4 n-tiles x 4 k-steps of 16x16x32 bf16.
// A-frag: lane holds AX[m=lane&15][k=quad*8+j] (doc-verified). B-frag:
// lane holds W2[k=quad*8+j][n=lane&15], read from transposed W2T[n][k].
// D: col(n)=lane&15, row(m)=quad*4+reg (doc-verified). In-place safe:
// wave reads/writes only its own 16 rows; stores data-depend on all loads.
__global__ __launch_bounds__(256) void update_mfma_kernel(
    const u16* __restrict__ hin, const u16* __restrict__ agg,
    const u16* __restrict__ W2T, const float* __restrict__ brel,
    u16* __restrict__ hout_bf, float* __restrict__ hout_f32, int relu)
{
    const int wave = threadIdx.x >> 6;
    const int lane = threadIdx.x & 63;
    const int nb16 = blockIdx.x * 64 + wave * 16;
    const int m = lane & 15;   // node-in-tile for A; out-dim-in-tile for B/D
    const int q = lane >> 4;   // quad

    int anode = nb16 + m;
    size_t rowa = (size_t)((anode < N_NODES) ? anode : 0) << 6;

    bf16x8 a[4];
    a[0] = *(const bf16x8*)(agg + rowa + q * 8);        // k  0..31
    a[1] = *(const bf16x8*)(agg + rowa + 32 + q * 8);   // k 32..63
    a[2] = *(const bf16x8*)(hin + rowa + q * 8);        // k 64..95
    a[3] = *(const bf16x8*)(hin + rowa + 32 + q * 8);   // k 96..127

    bf16x8 bfr[4][4];  // [ntile][kstep]
    #pragma unroll
    for (int nt = 0; nt < 4; ++nt)
        #pragma unroll
        for (int kk = 0; kk < 4; ++kk)
            bfr[nt][kk] = *(const bf16x8*)(W2T + (size_t)(nt * 16 + m) * 128
                                           + kk * 32 + q * 8);

    f32x4 acc[4];
    #pragma unroll
    for (int nt = 0; nt < 4; ++nt) {
        float bv = brel[nt * 16 + m];
        acc[nt] = (f32x4){bv, bv, bv, bv};
    }

    #pragma unroll
    for (int kk = 0; kk < 4; ++kk)
        #pragma unroll
        for (int nt = 0; nt < 4; ++nt)
            acc[nt] = __builtin_amdgcn_mfma_f32_16x16x32_bf16(
                a[kk], bfr[nt][kk], acc[nt], 0, 0, 0);

    #pragma unroll
    for (int nt = 0; nt < 4; ++nt)
        #pragma unroll
        for (int r = 0; r < 4; ++r) {
            int n2 = nb16 + q * 4 + r;           // node (row of D)
            if (n2 < N_NODES) {
                float v = acc[nt][r];
                if (relu) v = fmaxf(v, 0.f);
                int dim = nt * 16 + m;           // out dim (col of D)
                if (hout_f32) hout_f32[(size_t)n2 * 64 + dim] = v;
                else          hout_bf [(size_t)n2 * 64 + dim] = f2bf(v);
            }
        }
}

extern "C" void kernel_launch(void* const* d_in, const int* in_sizes, int n_in,
                              void* d_out, int out_size, void* d_ws, size_t ws_size,
                              hipStream_t stream)
{
    const float* x     = (const float*)d_in[0];
    const int*   ei    = (const int*)d_in[1];   // [2, E] int32
    const float* ew    = (const float*)d_in[2];
    const float* Wrel  = (const float*)d_in[3]; // [5, 64, 64]
    const float* brel  = (const float*)d_in[4]; // [5, 64]
    const float* Wroot = (const float*)d_in[5]; // [5, 64, 64]
    float* out = (float*)d_out;

    const int* src = ei;
    const int* dst = ei + N_EDGES;

    const size_t featb_bytes = (size_t)N_NODES * D * 2;  // 12.8 MB bf16
    char* ws = (char*)d_ws;
    size_t off = 0;
    u16*  hb     = (u16*)(ws + off);  off += featb_bytes;
    u16*  aggb   = (u16*)(ws + off);  off += featb_bytes;
    u16*  W2T    = (u16*)(ws + off);  off += (size_t)N_LAYERS * 64 * 128 * 2;
    int*  counts = (int*)(ws + off);  off += 400000;
    int*  rowptr = (int*)(ws + off);  off += 400016;
    int*  bsum   = (int*)(ws + off);  off += 2048;
    int*  bscan  = (int*)(ws + off);  off += 2048;
    int*  rcur   = (int*)(ws + off);  off += 64;
    int2* edges  = (int2*)(ws + off); off += (size_t)N_EDGES * 8;

    // Aliases, live only during CSR build (all dead before f2bf/agg run):
    //   kidx -> aggb[0 : 6.4MB]      (hist -> bin)
    //   wrec -> aggb[6.4 : 12.8MB]   (bin -> scatter)
    //   prec -> hb[0 : 6.4MB]        (bin -> scatter)
    //   srec -> hb[6.4 : 12.8MB]     (bin -> scatter)
    int*   kidx = (int*)aggb;
    float* wrec = (float*)((char*)aggb + (size_t)N_EDGES * 4);
    int*   prec = (int*)hb;
    int*   srec = (int*)((char*)hb + (size_t)N_EDGES * 4);

    const int eblocks = (N_EDGES + 255) / 256;       // 6250
    const int bblocks = N_EDGES / ABLK;              // 800
    const int sblocks = 8 * SC_NC;                   // 768
    const int cblocks = (N_NODES * D / 4 + 255) / 256;
    const int wblocks = (N_LAYERS * 64 * 128 + 255) / 256;  // 160
    const int ablocks = ((N_NODES + 1) / 2 + 3) / 4; // 12500 (2 nodes/wave)
    const int ublocks = (N_NODES + 63) / 64;         // 1563

    // ---- CSR build + converts ----
    hipMemsetAsync(counts, 0, N_NODES * sizeof(int), stream);
    hist_kernel<<<eblocks, 256, 0, stream>>>(dst, counts, kidx);
    scan_bsum_kernel<<<SCAN_BLOCKS, 256, 0, stream>>>(counts, bsum);
    scan_bscan_kernel<<<1, 512, 0, stream>>>(bsum, bscan, rowptr);
    scan_final_kernel<<<SCAN_BLOCKS, 256, 0, stream>>>(counts, bscan, rowptr);
    init_rcur_kernel<<<1, 64, 0, stream>>>(rowptr, rcur);
    bin_kernel<<<bblocks, 256, 0, stream>>>(src, dst, ew, kidx, rowptr, rcur,
                                            prec, srec, wrec);
    scatter_kernel<<<sblocks, 256, 0, stream>>>(prec, srec, wrec, rowptr, edges);
    f2bf_kernel<<<cblocks, 256, 0, stream>>>(x, hb);
    wprep_kernel<<<wblocks, 256, 0, stream>>>(Wrel, Wroot, W2T);

    // ---- 5 GraphConv layers (hb updated in place; wave-local rows) ----
    for (int layer = 0; layer < N_LAYERS; ++layer) {
        agg_kernel<<<ablocks, 256, 0, stream>>>(hb, rowptr, edges, aggb);
        int last = (layer == N_LAYERS - 1);
        update_mfma_kernel<<<ublocks, 256, 0, stream>>>(
            hb, aggb, W2T + (size_t)layer * 64 * 128,
            brel + (size_t)layer * D,
            last ? nullptr : hb, last ? out : nullptr,
            last ? 0 : 1);
    }
}

// Round 4
// 459.641 us; speedup vs baseline: 1.1313x; 1.0931x over previous
//
#include <hip/hip_runtime.h>

#define N_NODES 100000
#define N_EDGES 1600000
#define D 64
#define N_LAYERS 5
#define FB 1000          // fine buckets (counting sort), bucket = 100 nodes
#define BN 100           // nodes per bucket
#define BCAP 2048        // staging capacity per bucket (max bucket ~1600+5s)
#define BIN_BLOCKS 160
#define BIN_CHUNK 10000  // 160 * 10000 = 1.6M exactly

typedef unsigned short u16;
typedef unsigned long long u64;
typedef __attribute__((ext_vector_type(8))) short bf16x8;
typedef __attribute__((ext_vector_type(4))) float f32x4;

__device__ __forceinline__ float bf2f(u16 u) {
    union { unsigned int i; float f; } v;
    v.i = ((unsigned int)u) << 16;
    return v.f;
}
__device__ __forceinline__ u16 f2bf(float f) {
    union { float f; unsigned int i; } v;
    v.f = f;
    unsigned int r = v.i + 0x7FFFu + ((v.i >> 16) & 1u);  // round-nearest-even
    return (u16)(r >> 16);
}
__device__ __forceinline__ float bf2f_lo(unsigned int pk) {
    union { unsigned int i; float f; } v;
    v.i = pk << 16;
    return v.f;
}
__device__ __forceinline__ float bf2f_hi(unsigned int pk) {
    union { unsigned int i; float f; } v;
    v.i = pk & 0xFFFF0000u;
    return v.f;
}

// ====================== CSR build via 1000-bucket counting sort ==============
// Replaces hist (1.6M scattered device-scope atomics = 67us, 56MB of
// memory-side RMW writebacks) + 3 scan kernels + bin + scatter. Edge order
// within a node is free (sum is order-independent), so ranks can be assigned
// per-bucket locally in LDS; the only global atomics left are per-block
// per-bucket reservations (160K on a 4KB hot cursor array).
// Record = u64: low32 = {(d%100)<<17 | src}, high32 = bits(ew). u64 (not
// int2) because the nontemporal builtins only take scalar/vector-of-scalar.

__global__ __launch_bounds__(1024) void initcur_kernel(int* __restrict__ fcur)
{
    int b = threadIdx.x;
    if (b < FB) fcur[b] = b * BCAP;   // fixed-capacity staging segments
}

// Phase 1: bin edges into 1000 fine buckets (by dst/100). dst read plain
// (40KB/block chunk -> pass-2 re-read hits L1/L2); src/ew read once, nt (zero
// reuse, keep caches clean); staging stores nt. Reservations are ~10-record
// (80B) runs: interior lines full, boundary partial -> ~1.3x write amp on
// 12.8MB, acceptable.
__global__ __launch_bounds__(256) void bin_kernel(
    const int* __restrict__ src, const int* __restrict__ dst,
    const float* __restrict__ ew, int* __restrict__ fcur,
    u64* __restrict__ stag)
{
    __shared__ int hc[FB];
    for (int b = threadIdx.x; b < FB; b += 256) hc[b] = 0;
    __syncthreads();
    const int e0 = blockIdx.x * BIN_CHUNK;
    for (int e = e0 + threadIdx.x; e < e0 + BIN_CHUNK; e += 256) {
        int d = dst[e];
        atomicAdd(&hc[d / BN], 1);
    }
    __syncthreads();
    for (int b = threadIdx.x; b < FB; b += 256) {
        int c = hc[b];
        if (c) hc[b] = atomicAdd(&fcur[b], c);   // hc[b] becomes global cursor
    }
    __syncthreads();
    for (int e = e0 + threadIdx.x; e < e0 + BIN_CHUNK; e += 256) {
        int d = dst[e];                           // L1/L2-resident re-read
        int b = d / BN;
        int pos = atomicAdd(&hc[b], 1);           // LDS atomic -> global slot
        int s   = __builtin_nontemporal_load(&src[e]);
        float w = __builtin_nontemporal_load(&ew[e]);
        unsigned int pk = (unsigned int)((d - b * BN) << 17) | (unsigned int)s;
        u64 rec = ((u64)(unsigned int)__float_as_int(w) << 32) | pk;
        __builtin_nontemporal_store(rec, &stag[pos]);
    }
}

// Exclusive scan of bucket sizes -> fbase = CSR base per bucket (bucket order
// == node order, so staging index space maps 1:1 onto edges[] index space).
__global__ __launch_bounds__(1024) void fscan_kernel(
    const int* __restrict__ fcur, int* __restrict__ fbase,
    int* __restrict__ rowptr)
{
    __shared__ int s[1024];
    int t = threadIdx.x;
    int v = (t < FB) ? (fcur[t] - t * BCAP) : 0;   // bucket size
    s[t] = v;
    __syncthreads();
    for (int off = 1; off < 1024; off <<= 1) {
        int u = (t >= off) ? s[t - off] : 0;
        __syncthreads();
        s[t] += u;
        __syncthreads();
    }
    if (t < FB) fbase[t] = s[t] - v;
    if (t == FB - 1) {
        fbase[FB] = s[t];
        rowptr[N_NODES] = s[t];
    }
}

// Phase 2: one block per bucket. Stream segment into LDS + 100-counter
// histogram; tiny scan -> per-node rowptr AND local ranks; scatter into the
// bucket's contiguous ~12.8KB CSR slice (one block = one XCD = full-sector
// writebacks, round-1-verified). No global atomics at all.
__global__ __launch_bounds__(256) void sort_kernel(
    const u64* __restrict__ stag, const int* __restrict__ fbase,
    int* __restrict__ rowptr, int2* __restrict__ edges)
{
    __shared__ u64 ls[BCAP];       // 16 KB segment cache
    __shared__ int cnt[BN];
    __shared__ int cur[BN];
    __shared__ int sc[128];
    const int b = blockIdx.x;
    const int base = fbase[b];
    const int size = fbase[b + 1] - base;
    const int t = threadIdx.x;
    for (int i = t; i < BN; i += 256) cnt[i] = 0;
    __syncthreads();
    for (int i = t; i < size; i += 256) {
        u64 r = __builtin_nontemporal_load(&stag[b * BCAP + i]);
        ls[i] = r;
        atomicAdd(&cnt[((unsigned int)r) >> 17], 1);
    }
    __syncthreads();
    if (t < 128) sc[t] = (t < BN) ? cnt[t] : 0;
    __syncthreads();
    for (int off = 1; off < 128; off <<= 1) {
        int u = 0;
        if (t < 128 && t >= off) u = sc[t - off];
        __syncthreads();
        if (t < 128) sc[t] += u;
        __syncthreads();
    }
    if (t < BN) {
        int excl = sc[t] - cnt[t];
        rowptr[b * BN + t] = base + excl;
        cur[t] = excl;
    }
    __syncthreads();
    for (int i = t; i < size; i += 256) {
        u64 r = ls[i];
        unsigned int lo = (unsigned int)r;
        int dloc = lo >> 17;
        int rank = atomicAdd(&cur[dloc], 1);
        edges[base + rank] = make_int2((int)(lo & 0x1FFFFu),
                                       (int)(unsigned int)(r >> 32));
    }
}

// ======================= f32 -> bf16 convert (input x) =======================
__global__ __launch_bounds__(256) void f2bf_kernel(
    const float* __restrict__ in, u16* __restrict__ out)
{
    int i = blockIdx.x * 256 + threadIdx.x;   // one float4 per thread
    if (i >= (N_NODES * D) / 4) return;
    float4 v = ((const float4*)in)[i];
    ushort4 o;
    o.x = f2bf(v.x); o.y = f2bf(v.y); o.z = f2bf(v.z); o.w = f2bf(v.w);
    ((ushort4*)out)[i] = o;
}

// ================== Weight prep: W2T[l][n][k] bf16, k = [Wrel;Wroot] =========
__global__ __launch_bounds__(256) void wprep_kernel(
    const float* __restrict__ Wrel, const float* __restrict__ Wroot,
    u16* __restrict__ W2T)
{
    int i = blockIdx.x * 256 + threadIdx.x;  // over 5*64*128
    if (i >= N_LAYERS * 64 * 128) return;
    int l = i / (64 * 128);
    int rem = i % (64 * 128);
    int n = rem >> 7;   // out dim
    int k = rem & 127;  // input dim (0..63 = rel/agg, 64..127 = root/x)
    float v = (k < 64) ? Wrel[l * 4096 + k * 64 + n]
                       : Wroot[l * 4096 + (k - 64) * 64 + n];
    W2T[i] = f2bf(v);
}

// ========== Aggregation: 2 nodes per wave, bf16x2 dword gather ===============
// Lanes 0-31 serve node (2*wid), lanes 32-63 node (2*wid+1). Each lane loads
// a packed bf16x2 dword (dims 2sl, 2sl+1), so ONE load instruction fetches two
// full 128B rows (256B). Halves are fully independent: own edge list, own
// trip count (exec-mask divergence only), width-32 shuffles, no butterfly.
__global__ __launch_bounds__(256) void agg_kernel(
    const u16* __restrict__ h, const int* __restrict__ rowptr,
    const int2* __restrict__ edges, u16* __restrict__ agg)
{
    int wid  = (blockIdx.x * 256 + threadIdx.x) >> 6;
    int lane = threadIdx.x & 63;
    int sl   = lane & 31;           // sublane: dim pair -> dims 2sl, 2sl+1
    int node = wid * 2 + (lane >> 5);
    if (node >= N_NODES) return;
    int b = rowptr[node];
    int e = rowptr[node + 1];
    float acc0 = 0.f, acc1 = 0.f;
    for (int base = b; base < e; base += 32) {
        int cnt = min(32, e - base);
        int idx = 0;
        float wv = 0.f;
        if (sl < cnt) {
            int2 p = edges[base + sl];   // per-half coalesced 256B segment
            idx = p.x;
            wv = __int_as_float(p.y);
        }
        int j = 0;
        for (; j + 8 <= cnt; j += 8) {
            int s0 = __shfl(idx, j + 0, 32), s1 = __shfl(idx, j + 1, 32);
            int s2 = __shfl(idx, j + 2, 32), s3 = __shfl(idx, j + 3, 32);
            int s4 = __shfl(idx, j + 4, 32), s5 = __shfl(idx, j + 5, 32);
            int s6 = __shfl(idx, j + 6, 32), s7 = __shfl(idx, j + 7, 32);
            float w0 = __shfl(wv, j + 0, 32), w1 = __shfl(wv, j + 1, 32);
            float w2 = __shfl(wv, j + 2, 32), w3 = __shfl(wv, j + 3, 32);
            float w4 = __shfl(wv, j + 4, 32), w5 = __shfl(wv, j + 5, 32);
            float w6 = __shfl(wv, j + 6, 32), w7 = __shfl(wv, j + 7, 32);
            unsigned int p0 = *(const unsigned int*)(h + ((size_t)s0 << 6) + sl * 2);
            unsigned int p1 = *(const unsigned int*)(h + ((size_t)s1 << 6) + sl * 2);
            unsigned int p2 = *(const unsigned int*)(h + ((size_t)s2 << 6) + sl * 2);
            unsigned int p3 = *(const unsigned int*)(h + ((size_t)s3 << 6) + sl * 2);
            unsigned int p4 = *(const unsigned int*)(h + ((size_t)s4 << 6) + sl * 2);
            unsigned int p5 = *(const unsigned int*)(h + ((size_t)s5 << 6) + sl * 2);
            unsigned int p6 = *(const unsigned int*)(h + ((size_t)s6 << 6) + sl * 2);
            unsigned int p7 = *(const unsigned int*)(h + ((size_t)s7 << 6) + sl * 2);
            acc0 += bf2f_lo(p0) * w0 + bf2f_lo(p1) * w1
                  + bf2f_lo(p2) * w2 + bf2f_lo(p3) * w3
                  + bf2f_lo(p4) * w4 + bf2f_lo(p5) * w5
                  + bf2f_lo(p6) * w6 + bf2f_lo(p7) * w7;
            acc1 += bf2f_hi(p0) * w0 + bf2f_hi(p1) * w1
                  + bf2f_hi(p2) * w2 + bf2f_hi(p3) * w3
                  + bf2f_hi(p4) * w4 + bf2f_hi(p5) * w5
                  + bf2f_hi(p6) * w6 + bf2f_hi(p7) * w7;
        }
        for (; j < cnt; ++j) {
            int s = __shfl(idx, j, 32);
            float w = __shfl(wv, j, 32);
            unsigned int pk = *(const unsigned int*)(h + ((size_t)s << 6) + sl * 2);
            acc0 += bf2f_lo(pk) * w;
            acc1 += bf2f_hi(pk) * w;
        }
    }
    unsigned int o = ((unsigned int)f2bf(acc1) << 16) | f2bf(acc0);
    *(unsigned int*)(agg + ((size_t)node << 6) + sl * 2) = o;
}

// =================== Dense update via MFMA (no LDS, no barrier) ==============
// Wave = 16 nodes x 64 out-dims = 4 n-tiles x 4 k-steps of 16x16x32 bf16.
// A-frag: lane holds AX[m=lane&15][k=quad*8+j] (doc-verified). B-frag:
// lane holds W2[k=quad*8+j][n=lane&15], read from transposed W2T[n][k].
// D: col(n)=lane&15, row(m)=quad*4+reg (doc-verified). In-place safe:
// wave reads/writes only its own 16 rows; stores data-depend on all loads.
__global__ __launch_bounds__(256) void update_mfma_kernel(
    const u16* __restrict__ hin, const u16* __restrict__ agg,
    const u16* __restrict__ W2T, const float* __restrict__ brel,
    u16* __restrict__ hout_bf, float* __restrict__ hout_f32, int relu)
{
    const int wave = threadIdx.x >> 6;
    const int lane = threadIdx.x & 63;
    const int nb16 = blockIdx.x * 64 + wave * 16;
    const int m = lane & 15;   // node-in-tile for A; out-dim-in-tile for B/D
    const int q = lane >> 4;   // quad

    int anode = nb16 + m;
    size_t rowa = (size_t)((anode < N_NODES) ? anode : 0) << 6;

    bf16x8 a[4];
    a[0] = *(const bf16x8*)(agg + rowa + q * 8);        // k  0..31
    a[1] = *(const bf16x8*)(agg + rowa + 32 + q * 8);   // k 32..63
    a[2] = *(const bf16x8*)(hin + rowa + q * 8);        // k 64..95
    a[3] = *(const bf16x8*)(hin + rowa + 32 + q * 8);   // k 96..127

    bf16x8 bfr[4][4];  // [ntile][kstep]
    #pragma unroll
    for (int nt = 0; nt < 4; ++nt)
        #pragma unroll
        for (int kk = 0; kk < 4; ++kk)
            bfr[nt][kk] = *(const bf16x8*)(W2T + (size_t)(nt * 16 + m) * 128
                                           + kk * 32 + q * 8);

    f32x4 acc[4];
    #pragma unroll
    for (int nt = 0; nt < 4; ++nt) {
        float bv = brel[nt * 16 + m];
        acc[nt] = (f32x4){bv, bv, bv, bv};
    }

    #pragma unroll
    for (int kk = 0; kk < 4; ++kk)
        #pragma unroll
        for (int nt = 0; nt < 4; ++nt)
            acc[nt] = __builtin_amdgcn_mfma_f32_16x16x32_bf16(
                a[kk], bfr[nt][kk], acc[nt], 0, 0, 0);

    #pragma unroll
    for (int nt = 0; nt < 4; ++nt)
        #pragma unroll
        for (int r = 0; r < 4; ++r) {
            int n2 = nb16 + q * 4 + r;           // node (row of D)
            if (n2 < N_NODES) {
                float v = acc[nt][r];
                if (relu) v = fmaxf(v, 0.f);
                int dim = nt * 16 + m;           // out dim (col of D)
                if (hout_f32) hout_f32[(size_t)n2 * 64 + dim] = v;
                else          hout_bf [(size_t)n2 * 64 + dim] = f2bf(v);
            }
        }
}

extern "C" void kernel_launch(void* const* d_in, const int* in_sizes, int n_in,
                              void* d_out, int out_size, void* d_ws, size_t ws_size,
                              hipStream_t stream)
{
    const float* x     = (const float*)d_in[0];
    const int*   ei    = (const int*)d_in[1];   // [2, E] int32
    const float* ew    = (const float*)d_in[2];
    const float* Wrel  = (const float*)d_in[3]; // [5, 64, 64]
    const float* brel  = (const float*)d_in[4]; // [5, 64]
    const float* Wroot = (const float*)d_in[5]; // [5, 64, 64]
    float* out = (float*)d_out;

    const int* src = ei;
    const int* dst = ei + N_EDGES;

    const size_t featb_bytes = (size_t)N_NODES * D * 2;  // 12.8 MB bf16
    char* ws = (char*)d_ws;
    size_t off = 0;
    u16*  hb     = (u16*)(ws + off);  off += featb_bytes;
    u16*  aggb   = (u16*)(ws + off);  off += featb_bytes;
    u16*  W2T    = (u16*)(ws + off);  off += (size_t)N_LAYERS * 64 * 128 * 2;
    int*  rowptr = (int*)(ws + off);  off += 400016;
    int*  fcur   = (int*)(ws + off);  off += FB * 4;
    int*  fbase  = (int*)(ws + off);  off += (FB + 1) * 4 + 60;
    int2* edges  = (int2*)(ws + off); off += (size_t)N_EDGES * 8;

    // stag aliases hb+aggb (16.4 MB < 25.6 MB): live only bin -> sort, both
    // complete (stream-ordered) before f2bf writes hb / agg writes aggb.
    u64* stag = (u64*)ws;

    const int cblocks = (N_NODES * D / 4 + 255) / 256;
    const int wblocks = (N_LAYERS * 64 * 128 + 255) / 256;  // 160
    const int ablocks = ((N_NODES + 1) / 2 + 3) / 4; // 12500 (2 nodes/wave)
    const int ublocks = (N_NODES + 63) / 64;         // 1563

    // ---- CSR build (counting sort) + converts ----
    initcur_kernel<<<1, 1024, 0, stream>>>(fcur);
    bin_kernel<<<BIN_BLOCKS, 256, 0, stream>>>(src, dst, ew, fcur, stag);
    fscan_kernel<<<1, 1024, 0, stream>>>(fcur, fbase, rowptr);
    sort_kernel<<<FB, 256, 0, stream>>>(stag, fbase, rowptr, edges);
    f2bf_kernel<<<cblocks, 256, 0, stream>>>(x, hb);
    wprep_kernel<<<wblocks, 256, 0, stream>>>(Wrel, Wroot, W2T);

    // ---- 5 GraphConv layers (hb updated in place; wave-local rows) ----
    for (int layer = 0; layer < N_LAYERS; ++layer) {
        agg_kernel<<<ablocks, 256, 0, stream>>>(hb, rowptr, edges, aggb);
        int last = (layer == N_LAYERS - 1);
        update_mfma_kernel<<<ublocks, 256, 0, stream>>>(
            hb, aggb, W2T + (size_t)layer * 64 * 128,
            brel + (size_t)layer * D,
            last ? nullptr : hb, last ? out : nullptr,
            last ? 0 : 1);
    }
}

// Round 5
// 426.599 us; speedup vs baseline: 1.2189x; 1.0775x over previous
//
#include <hip/hip_runtime.h>

#define N_NODES 100000
#define N_EDGES 1600000
#define D 64
#define N_LAYERS 5
#define FB 1000          // fine buckets (counting sort), bucket = 100 nodes
#define BN 100           // nodes per bucket
#define BCAP 2048        // staging capacity per bucket (max bucket ~1600+11s)
#define BIN_BLOCKS 256
#define BIN_THREADS 512
#define BIN_CHUNK 6250   // 256 * 6250 = 1.6M exactly

typedef unsigned short u16;
typedef unsigned long long u64;
typedef __attribute__((ext_vector_type(8))) short bf16x8;
typedef __attribute__((ext_vector_type(4))) float f32x4;

__device__ __forceinline__ float bf2f(u16 u) {
    union { unsigned int i; float f; } v;
    v.i = ((unsigned int)u) << 16;
    return v.f;
}
__device__ __forceinline__ u16 f2bf(float f) {
    union { float f; unsigned int i; } v;
    v.f = f;
    unsigned int r = v.i + 0x7FFFu + ((v.i >> 16) & 1u);  // round-nearest-even
    return (u16)(r >> 16);
}
__device__ __forceinline__ float bf2f_lo(unsigned int pk) {
    union { unsigned int i; float f; } v;
    v.i = pk << 16;
    return v.f;
}
__device__ __forceinline__ float bf2f_hi(unsigned int pk) {
    union { unsigned int i; float f; } v;
    v.i = pk & 0xFFFF0000u;
    return v.f;
}

// ====================== CSR build via 1000-bucket counting sort ==============
// Record = u64: low32 = {(d%100)<<17 | src}, high32 = bits(ew).
// Round-4 lesson: staging stores must be PLAIN (nt stores defeat L2 write
// merging -> 75MB writeback for 12.8MB data), and the grid must cover all
// 256 CUs (160 blocks = 5.8% occupancy, latency-bound).

__global__ __launch_bounds__(1024) void initcur_kernel(int* __restrict__ fcur)
{
    int b = threadIdx.x;
    if (b < FB) fcur[b] = b * BCAP;   // fixed-capacity staging segments
}

// Phase 1: bin edges into 1000 fine buckets (by dst/100). dst read plain
// (25KB/block chunk -> pass-2 re-read hits L1/L2); src/ew read once, nt (zero
// reuse); staging stores PLAIN so the ~6-record reservation runs merge in L2
// (per-XCD write working set ~2MB < 4MB L2) and write back full sectors.
__global__ __launch_bounds__(BIN_THREADS) void bin_kernel(
    const int* __restrict__ src, const int* __restrict__ dst,
    const float* __restrict__ ew, int* __restrict__ fcur,
    u64* __restrict__ stag)
{
    __shared__ int hc[FB];
    for (int b = threadIdx.x; b < FB; b += BIN_THREADS) hc[b] = 0;
    __syncthreads();
    const int e0 = blockIdx.x * BIN_CHUNK;
    for (int e = e0 + threadIdx.x; e < e0 + BIN_CHUNK; e += BIN_THREADS) {
        int d = dst[e];
        atomicAdd(&hc[d / BN], 1);
    }
    __syncthreads();
    for (int b = threadIdx.x; b < FB; b += BIN_THREADS) {
        int c = hc[b];
        if (c) hc[b] = atomicAdd(&fcur[b], c);   // hc[b] becomes global cursor
    }
    __syncthreads();
    for (int e = e0 + threadIdx.x; e < e0 + BIN_CHUNK; e += BIN_THREADS) {
        int d = dst[e];                           // L1/L2-resident re-read
        int b = d / BN;
        int pos = atomicAdd(&hc[b], 1);           // LDS atomic -> global slot
        int s   = __builtin_nontemporal_load(&src[e]);
        float w = __builtin_nontemporal_load(&ew[e]);
        unsigned int pk = (unsigned int)((d - b * BN) << 17) | (unsigned int)s;
        u64 rec = ((u64)(unsigned int)__float_as_int(w) << 32) | pk;
        stag[pos] = rec;                          // plain: L2 write-merge
    }
}

// Exclusive scan of bucket sizes -> fbase = CSR base per bucket (bucket order
// == node order, so staging index space maps 1:1 onto edges[] index space).
__global__ __launch_bounds__(1024) void fscan_kernel(
    const int* __restrict__ fcur, int* __restrict__ fbase,
    int* __restrict__ rowptr)
{
    __shared__ int s[1024];
    int t = threadIdx.x;
    int v = (t < FB) ? (fcur[t] - t * BCAP) : 0;   // bucket size
    s[t] = v;
    __syncthreads();
    for (int off = 1; off < 1024; off <<= 1) {
        int u = (t >= off) ? s[t - off] : 0;
        __syncthreads();
        s[t] += u;
        __syncthreads();
    }
    if (t < FB) fbase[t] = s[t] - v;
    if (t == FB - 1) {
        fbase[FB] = s[t];
        rowptr[N_NODES] = s[t];
    }
}

// Phase 2: one block per bucket. Stream segment into LDS + 100-counter
// histogram; tiny scan -> per-node rowptr AND local ranks; scatter into the
// bucket's contiguous ~12.8KB CSR slice (one block = one XCD = full-sector
// writebacks, round-1-verified). No global atomics at all.
__global__ __launch_bounds__(256) void sort_kernel(
    const u64* __restrict__ stag, const int* __restrict__ fbase,
    int* __restrict__ rowptr, int2* __restrict__ edges)
{
    __shared__ u64 ls[BCAP];       // 16 KB segment cache
    __shared__ int cnt[BN];
    __shared__ int cur[BN];
    __shared__ int sc[128];
    const int b = blockIdx.x;
    const int base = fbase[b];
    const int size = fbase[b + 1] - base;
    const int t = threadIdx.x;
    for (int i = t; i < BN; i += 256) cnt[i] = 0;
    __syncthreads();
    for (int i = t; i < size; i += 256) {
        u64 r = __builtin_nontemporal_load(&stag[b * BCAP + i]);
        ls[i] = r;
        atomicAdd(&cnt[((unsigned int)r) >> 17], 1);
    }
    __syncthreads();
    if (t < 128) sc[t] = (t < BN) ? cnt[t] : 0;
    __syncthreads();
    for (int off = 1; off < 128; off <<= 1) {
        int u = 0;
        if (t < 128 && t >= off) u = sc[t - off];
        __syncthreads();
        if (t < 128) sc[t] += u;
        __syncthreads();
    }
    if (t < BN) {
        int excl = sc[t] - cnt[t];
        rowptr[b * BN + t] = base + excl;
        cur[t] = excl;
    }
    __syncthreads();
    for (int i = t; i < size; i += 256) {
        u64 r = ls[i];
        unsigned int lo = (unsigned int)r;
        int dloc = lo >> 17;
        int rank = atomicAdd(&cur[dloc], 1);
        edges[base + rank] = make_int2((int)(lo & 0x1FFFFu),
                                       (int)(unsigned int)(r >> 32));
    }
}

// ======================= f32 -> bf16 convert (input x) =======================
__global__ __launch_bounds__(256) void f2bf_kernel(
    const float* __restrict__ in, u16* __restrict__ out)
{
    int i = blockIdx.x * 256 + threadIdx.x;   // one float4 per thread
    if (i >= (N_NODES * D) / 4) return;
    float4 v = ((const float4*)in)[i];
    ushort4 o;
    o.x = f2bf(v.x); o.y = f2bf(v.y); o.z = f2bf(v.z); o.w = f2bf(v.w);
    ((ushort4*)out)[i] = o;
}

// ================== Weight prep: W2T[l][n][k] bf16, k = [Wrel;Wroot] =========
__global__ __launch_bounds__(256) void wprep_kernel(
    const float* __restrict__ Wrel, const float* __restrict__ Wroot,
    u16* __restrict__ W2T)
{
    int i = blockIdx.x * 256 + threadIdx.x;  // over 5*64*128
    if (i >= N_LAYERS * 64 * 128) return;
    int l = i / (64 * 128);
    int rem = i % (64 * 128);
    int n = rem >> 7;   // out dim
    int k = rem & 127;  // input dim (0..63 = rel/agg, 64..127 = root/x)
    float v = (k < 64) ? Wrel[l * 4096 + k * 64 + n]
                       : Wroot[l * 4096 + (k - 64) * 64 + n];
    W2T[i] = f2bf(v);
}

// ========== Aggregation: 2 nodes per wave, bf16x2 dword gather ===============
// Lanes 0-31 serve node (2*wid), lanes 32-63 node (2*wid+1). Each lane loads
// a packed bf16x2 dword (dims 2sl, 2sl+1), so ONE load instruction fetches two
// full 128B rows (256B). Halves are fully independent: own edge list, own
// trip count (exec-mask divergence only), width-32 shuffles, no butterfly.
__global__ __launch_bounds__(256) void agg_kernel(
    const u16* __restrict__ h, const int* __restrict__ rowptr,
    const int2* __restrict__ edges, u16* __restrict__ agg)
{
    int wid  = (blockIdx.x * 256 + threadIdx.x) >> 6;
    int lane = threadIdx.x & 63;
    int sl   = lane & 31;           // sublane: dim pair -> dims 2sl, 2sl+1
    int node = wid * 2 + (lane >> 5);
    if (node >= N_NODES) return;
    int b = rowptr[node];
    int e = rowptr[node + 1];
    float acc0 = 0.f, acc1 = 0.f;
    for (int base = b; base < e; base += 32) {
        int cnt = min(32, e - base);
        int idx = 0;
        float wv = 0.f;
        if (sl < cnt) {
            int2 p = edges[base + sl];   // per-half coalesced 256B segment
            idx = p.x;
            wv = __int_as_float(p.y);
        }
        int j = 0;
        for (; j + 8 <= cnt; j += 8) {
            int s0 = __shfl(idx, j + 0, 32), s1 = __shfl(idx, j + 1, 32);
            int s2 = __shfl(idx, j + 2, 32), s3 = __shfl(idx, j + 3, 32);
            int s4 = __shfl(idx, j + 4, 32), s5 = __shfl(idx, j + 5, 32);
            int s6 = __shfl(idx, j + 6, 32), s7 = __shfl(idx, j + 7, 32);
            float w0 = __shfl(wv, j + 0, 32), w1 = __shfl(wv, j + 1, 32);
            float w2 = __shfl(wv, j + 2, 32), w3 = __shfl(wv, j + 3, 32);
            float w4 = __shfl(wv, j + 4, 32), w5 = __shfl(wv, j + 5, 32);
            float w6 = __shfl(wv, j + 6, 32), w7 = __shfl(wv, j + 7, 32);
            unsigned int p0 = *(const unsigned int*)(h + ((size_t)s0 << 6) + sl * 2);
            unsigned int p1 = *(const unsigned int*)(h + ((size_t)s1 << 6) + sl * 2);
            unsigned int p2 = *(const unsigned int*)(h + ((size_t)s2 << 6) + sl * 2);
            unsigned int p3 = *(const unsigned int*)(h + ((size_t)s3 << 6) + sl * 2);
            unsigned int p4 = *(const unsigned int*)(h + ((size_t)s4 << 6) + sl * 2);
            unsigned int p5 = *(const unsigned int*)(h + ((size_t)s5 << 6) + sl * 2);
            unsigned int p6 = *(const unsigned int*)(h + ((size_t)s6 << 6) + sl * 2);
            unsigned int p7 = *(const unsigned int*)(h + ((size_t)s7 << 6) + sl * 2);
            acc0 += bf2f_lo(p0) * w0 + bf2f_lo(p1) * w1
                  + bf2f_lo(p2) * w2 + bf2f_lo(p3) * w3
                  + bf2f_lo(p4) * w4 + bf2f_lo(p5) * w5
                  + bf2f_lo(p6) * w6 + bf2f_lo(p7) * w7;
            acc1 += bf2f_hi(p0) * w0 + bf2f_hi(p1) * w1
                  + bf2f_hi(p2) * w2 + bf2f_hi(p3) * w3
                  + bf2f_hi(p4) * w4 + bf2f_hi(p5) * w5
                  + bf2f_hi(p6) * w6 + bf2f_hi(p7) * w7;
        }
        for (; j < cnt; ++j) {
            int s = __shfl(idx, j, 32);
            float w = __shfl(wv, j, 32);
            unsigned int pk = *(const unsigned int*)(h + ((size_t)s << 6) + sl * 2);
            acc0 += bf2f_lo(pk) * w;
            acc1 += bf2f_hi(pk) * w;
        }
    }
    unsigned int o = ((unsigned int)f2bf(acc1) << 16) | f2bf(acc0);
    *(unsigned int*)(agg + ((size_t)node << 6) + sl * 2) = o;
}

// =================== Dense update via MFMA (no LDS, no barrier) ==============
// Wave = 16 nodes x 64 out-dims = 4 n-tiles x 4 k-steps of 16x16x32 bf16.
// A-frag: lane holds AX[m=lane&15][k=quad*8+j] (doc-verified). B-frag:
// lane holds W2[k=quad*8+j][n=lane&15], read from transposed W2T[n][k].
// D: col(n)=lane&15, row(m)=quad*4+reg (doc-verified). In-place safe:
// wave reads/writes only its own 16 rows; stores data-depend on all loads.
__global__ __launch_bounds__(256) void update_mfma_kernel(
    const u16* __restrict__ hin, const u16* __restrict__ agg,
    const u16* __restrict__ W2T, const float* __restrict__ brel,
    u16* __restrict__ hout_bf, float* __restrict__ hout_f32, int relu)
{
    const int wave = threadIdx.x >> 6;
    const int lane = threadIdx.x & 63;
    const int nb16 = blockIdx.x * 64 + wave * 16;
    const int m = lane & 15;   // node-in-tile for A; out-dim-in-tile for B/D
    const int q = lane >> 4;   // quad

    int anode = nb16 + m;
    size_t rowa = (size_t)((anode < N_NODES) ? anode : 0) << 6;

    bf16x8 a[4];
    a[0] = *(const bf16x8*)(agg + rowa + q * 8);        // k  0..31
    a[1] = *(const bf16x8*)(agg + rowa + 32 + q * 8);   // k 32..63
    a[2] = *(const bf16x8*)(hin + rowa + q * 8);        // k 64..95
    a[3] = *(const bf16x8*)(hin + rowa + 32 + q * 8);   // k 96..127

    bf16x8 bfr[4][4];  // [ntile][kstep]
    #pragma unroll
    for (int nt = 0; nt < 4; ++nt)
        #pragma unroll
        for (int kk = 0; kk < 4; ++kk)
            bfr[nt][kk] = *(const bf16x8*)(W2T + (size_t)(nt * 16 + m) * 128
                                           + kk * 32 + q * 8);

    f32x4 acc[4];
    #pragma unroll
    for (int nt = 0; nt < 4; ++nt) {
        float bv = brel[nt * 16 + m];
        acc[nt] = (f32x4){bv, bv, bv, bv};
    }

    #pragma unroll
    for (int kk = 0; kk < 4; ++kk)
        #pragma unroll
        for (int nt = 0; nt < 4; ++nt)
            acc[nt] = __builtin_amdgcn_mfma_f32_16x16x32_bf16(
                a[kk], bfr[nt][kk], acc[nt], 0, 0, 0);

    #pragma unroll
    for (int nt = 0; nt < 4; ++nt)
        #pragma unroll
        for (int r = 0; r < 4; ++r) {
            int n2 = nb16 + q * 4 + r;           // node (row of D)
            if (n2 < N_NODES) {
                float v = acc[nt][r];
                if (relu) v = fmaxf(v, 0.f);
                int dim = nt * 16 + m;           // out dim (col of D)
                if (hout_f32) hout_f32[(size_t)n2 * 64 + dim] = v;
                else          hout_bf [(size_t)n2 * 64 + dim] = f2bf(v);
            }
        }
}

extern "C" void kernel_launch(void* const* d_in, const int* in_sizes, int n_in,
                              void* d_out, int out_size, void* d_ws, size_t ws_size,
                              hipStream_t stream)
{
    const float* x     = (const float*)d_in[0];
    const int*   ei    = (const int*)d_in[1];   // [2, E] int32
    const float* ew    = (const float*)d_in[2];
    const float* Wrel  = (const float*)d_in[3]; // [5, 64, 64]
    const float* brel  = (const float*)d_in[4]; // [5, 64]
    const float* Wroot = (const float*)d_in[5]; // [5, 64, 64]
    float* out = (float*)d_out;

    const int* src = ei;
    const int* dst = ei + N_EDGES;

    const size_t featb_bytes = (size_t)N_NODES * D * 2;  // 12.8 MB bf16
    char* ws = (char*)d_ws;
    size_t off = 0;
    u16*  hb     = (u16*)(ws + off);  off += featb_bytes;
    u16*  aggb   = (u16*)(ws + off);  off += featb_bytes;
    u16*  W2T    = (u16*)(ws + off);  off += (size_t)N_LAYERS * 64 * 128 * 2;
    int*  rowptr = (int*)(ws + off);  off += 400016;
    int*  fcur   = (int*)(ws + off);  off += FB * 4;
    int*  fbase  = (int*)(ws + off);  off += (FB + 1) * 4 + 60;
    int2* edges  = (int2*)(ws + off); off += (size_t)N_EDGES * 8;

    // stag aliases hb+aggb (16.4 MB < 25.6 MB): live only bin -> sort, both
    // complete (stream-ordered) before f2bf writes hb / agg writes aggb.
    u64* stag = (u64*)ws;

    const int cblocks = (N_NODES * D / 4 + 255) / 256;
    const int wblocks = (N_LAYERS * 64 * 128 + 255) / 256;  // 160
    const int ablocks = ((N_NODES + 1) / 2 + 3) / 4; // 12500 (2 nodes/wave)
    const int ublocks = (N_NODES + 63) / 64;         // 1563

    // ---- CSR build (counting sort) + converts ----
    initcur_kernel<<<1, 1024, 0, stream>>>(fcur);
    bin_kernel<<<BIN_BLOCKS, BIN_THREADS, 0, stream>>>(src, dst, ew, fcur, stag);
    fscan_kernel<<<1, 1024, 0, stream>>>(fcur, fbase, rowptr);
    sort_kernel<<<FB, 256, 0, stream>>>(stag, fbase, rowptr, edges);
    f2bf_kernel<<<cblocks, 256, 0, stream>>>(x, hb);
    wprep_kernel<<<wblocks, 256, 0, stream>>>(Wrel, Wroot, W2T);

    // ---- 5 GraphConv layers (hb updated in place; wave-local rows) ----
    for (int layer = 0; layer < N_LAYERS; ++layer) {
        agg_kernel<<<ablocks, 256, 0, stream>>>(hb, rowptr, edges, aggb);
        int last = (layer == N_LAYERS - 1);
        update_mfma_kernel<<<ublocks, 256, 0, stream>>>(
            hb, aggb, W2T + (size_t)layer * 64 * 128,
            brel + (size_t)layer * D,
            last ? nullptr : hb, last ? out : nullptr,
            last ? 0 : 1);
    }
}

// Round 6
// 412.834 us; speedup vs baseline: 1.2596x; 1.0333x over previous
//
#include <hip/hip_runtime.h>

#define N_NODES 100000
#define N_EDGES 1600000
#define D 64
#define N_LAYERS 5
#define FB 1000          // fine buckets (counting sort), bucket = 100 nodes
#define BN 100           // nodes per bucket
#define NX 8             // XCD partitions of the staging array
#define BCAP_X 320       // staging capacity per (xcd,bucket) cell; mean 200,
                         // sigma ~14 -> 8.5 sigma headroom; 320*8B = 64B-mult
#define BCAP 2048        // max records per bucket in sort (mean 1600 + 11s)
#define BIN_BLOCKS 512
#define BIN_THREADS 512
#define BIN_CHUNK 3125   // 512 * 3125 = 1.6M exactly

typedef unsigned short u16;
typedef unsigned long long u64;
typedef __attribute__((ext_vector_type(8))) short bf16x8;
typedef __attribute__((ext_vector_type(4))) float f32x4;

__device__ __forceinline__ float bf2f(u16 u) {
    union { unsigned int i; float f; } v;
    v.i = ((unsigned int)u) << 16;
    return v.f;
}
__device__ __forceinline__ u16 f2bf(float f) {
    union { float f; unsigned int i; } v;
    v.f = f;
    unsigned int r = v.i + 0x7FFFu + ((v.i >> 16) & 1u);  // round-nearest-even
    return (u16)(r >> 16);
}
__device__ __forceinline__ float bf2f_lo(unsigned int pk) {
    union { unsigned int i; float f; } v;
    v.i = pk << 16;
    return v.f;
}
__device__ __forceinline__ float bf2f_hi(unsigned int pk) {
    union { unsigned int i; float f; } v;
    v.i = pk & 0xFFFF0000u;
    return v.f;
}

// ====================== CSR build via 1000-bucket counting sort ==============
// Record = u64: low32 = {(d%100)<<17 | src}, high32 = bits(ew).
// Round-5 lesson: with XCD-shared staging cells, adjacent ~50B reservation
// runs come from different XCDs, so nearly every 64B line is written
// partially by >=2 L2s -> 3.2x write amp (42MB vs 13MB). Fix: partition
// staging into 8000 cells = (xcd = blockIdx%8) x bucket, 64B-aligned. A cell
// is written by ONE XCD only; its L2 merges runs of any length (hot set =
// 1000 tail lines = 64KB). Run length no longer matters -> grid doubled to
// 512 blocks for latency hiding (round-5: 15% occupancy, 2% VALU).

__global__ __launch_bounds__(1024) void initcur_kernel(int* __restrict__ fcur)
{
    int i = blockIdx.x * 1024 + threadIdx.x;
    if (i < NX * FB) fcur[i] = i * BCAP_X;   // fixed-capacity staging cells
}

// Phase 1: bin edges into 1000 fine buckets (by dst/100), staging into this
// block's XCD partition. dst read plain (12.5KB chunk -> pass-2 re-read hits
// L1); src/ew read once, nt (zero reuse); staging stores plain (L2 merge).
__global__ __launch_bounds__(BIN_THREADS) void bin_kernel(
    const int* __restrict__ src, const int* __restrict__ dst,
    const float* __restrict__ ew, int* __restrict__ fcur,
    u64* __restrict__ stag)
{
    __shared__ int hc[FB];
    const int xbase = (blockIdx.x & (NX - 1)) * FB;   // this XCD's cell row
    for (int b = threadIdx.x; b < FB; b += BIN_THREADS) hc[b] = 0;
    __syncthreads();
    const int e0 = blockIdx.x * BIN_CHUNK;
    for (int e = e0 + threadIdx.x; e < e0 + BIN_CHUNK; e += BIN_THREADS) {
        int d = dst[e];
        atomicAdd(&hc[d / BN], 1);
    }
    __syncthreads();
    for (int b = threadIdx.x; b < FB; b += BIN_THREADS) {
        int c = hc[b];
        if (c) hc[b] = atomicAdd(&fcur[xbase + b], c);  // -> global cursor
    }
    __syncthreads();
    for (int e = e0 + threadIdx.x; e < e0 + BIN_CHUNK; e += BIN_THREADS) {
        int d = dst[e];                           // L1-resident re-read
        int b = d / BN;
        int pos = atomicAdd(&hc[b], 1);           // LDS atomic -> global slot
        int s   = __builtin_nontemporal_load(&src[e]);
        float w = __builtin_nontemporal_load(&ew[e]);
        unsigned int pk = (unsigned int)((d - b * BN) << 17) | (unsigned int)s;
        u64 rec = ((u64)(unsigned int)__float_as_int(w) << 32) | pk;
        stag[pos] = rec;                          // plain: L2 write-merge
    }
}

// Exclusive scan of bucket sizes (summing the 8 XCD cells per bucket) ->
// fbase = CSR base per bucket (bucket order == node order).
__global__ __launch_bounds__(1024) void fscan_kernel(
    const int* __restrict__ fcur, int* __restrict__ fbase,
    int* __restrict__ rowptr)
{
    __shared__ int s[1024];
    int t = threadIdx.x;
    int v = 0;
    if (t < FB) {
        #pragma unroll
        for (int x = 0; x < NX; ++x) {
            int cell = x * FB + t;
            v += fcur[cell] - cell * BCAP_X;      // cell size
        }
    }
    s[t] = v;
    __syncthreads();
    for (int off = 1; off < 1024; off <<= 1) {
        int u = (t >= off) ? s[t - off] : 0;
        __syncthreads();
        s[t] += u;
        __syncthreads();
    }
    if (t < FB) fbase[t] = s[t] - v;
    if (t == FB - 1) {
        fbase[FB] = s[t];
        rowptr[N_NODES] = s[t];
    }
}

// Phase 2: one block per bucket. Stream the bucket's 8 XCD sub-segments into
// LDS + 100-counter histogram; tiny scan -> per-node rowptr AND local ranks;
// scatter into the bucket's contiguous ~12.8KB CSR slice (one block = one
// XCD = full-sector writebacks). No global atomics at all.
__global__ __launch_bounds__(256) void sort_kernel(
    const u64* __restrict__ stag, const int* __restrict__ fcur,
    const int* __restrict__ fbase, int* __restrict__ rowptr,
    int2* __restrict__ edges)
{
    __shared__ u64 ls[BCAP];       // 16 KB segment cache
    __shared__ int cnt[BN];
    __shared__ int cur[BN];
    __shared__ int sc[128];
    const int b = blockIdx.x;
    const int base = fbase[b];
    const int t = threadIdx.x;
    for (int i = t; i < BN; i += 256) cnt[i] = 0;
    __syncthreads();
    int ofs = 0;
    #pragma unroll
    for (int x = 0; x < NX; ++x) {
        int cell = x * FB + b;
        int sz = fcur[cell] - cell * BCAP_X;      // uniform scalar load
        const u64* sp = stag + (size_t)cell * BCAP_X;
        for (int i = t; i < sz; i += 256) {
            u64 r = __builtin_nontemporal_load(&sp[i]);
            ls[ofs + i] = r;
            atomicAdd(&cnt[((unsigned int)r) >> 17], 1);
        }
        ofs += sz;
    }
    const int size = ofs;
    __syncthreads();
    if (t < 128) sc[t] = (t < BN) ? cnt[t] : 0;
    __syncthreads();
    for (int off = 1; off < 128; off <<= 1) {
        int u = 0;
        if (t < 128 && t >= off) u = sc[t - off];
        __syncthreads();
        if (t < 128) sc[t] += u;
        __syncthreads();
    }
    if (t < BN) {
        int excl = sc[t] - cnt[t];
        rowptr[b * BN + t] = base + excl;
        cur[t] = excl;
    }
    __syncthreads();
    for (int i = t; i < size; i += 256) {
        u64 r = ls[i];
        unsigned int lo = (unsigned int)r;
        int dloc = lo >> 17;
        int rank = atomicAdd(&cur[dloc], 1);
        edges[base + rank] = make_int2((int)(lo & 0x1FFFFu),
                                       (int)(unsigned int)(r >> 32));
    }
}

// ======================= f32 -> bf16 convert (input x) =======================
__global__ __launch_bounds__(256) void f2bf_kernel(
    const float* __restrict__ in, u16* __restrict__ out)
{
    int i = blockIdx.x * 256 + threadIdx.x;   // one float4 per thread
    if (i >= (N_NODES * D) / 4) return;
    float4 v = ((const float4*)in)[i];
    ushort4 o;
    o.x = f2bf(v.x); o.y = f2bf(v.y); o.z = f2bf(v.z); o.w = f2bf(v.w);
    ((ushort4*)out)[i] = o;
}

// ================== Weight prep: W2T[l][n][k] bf16, k = [Wrel;Wroot] =========
__global__ __launch_bounds__(256) void wprep_kernel(
    const float* __restrict__ Wrel, const float* __restrict__ Wroot,
    u16* __restrict__ W2T)
{
    int i = blockIdx.x * 256 + threadIdx.x;  // over 5*64*128
    if (i >= N_LAYERS * 64 * 128) return;
    int l = i / (64 * 128);
    int rem = i % (64 * 128);
    int n = rem >> 7;   // out dim
    int k = rem & 127;  // input dim (0..63 = rel/agg, 64..127 = root/x)
    float v = (k < 64) ? Wrel[l * 4096 + k * 64 + n]
                       : Wroot[l * 4096 + (k - 64) * 64 + n];
    W2T[i] = f2bf(v);
}

// ========== Aggregation: 2 nodes per wave, bf16x2 dword gather ===============
// Lanes 0-31 serve node (2*wid), lanes 32-63 node (2*wid+1). Each lane loads
// a packed bf16x2 dword (dims 2sl, 2sl+1), so ONE load instruction fetches two
// full 128B rows (256B). Halves are fully independent: own edge list, own
// trip count (exec-mask divergence only), width-32 shuffles, no butterfly.
__global__ __launch_bounds__(256) void agg_kernel(
    const u16* __restrict__ h, const int* __restrict__ rowptr,
    const int2* __restrict__ edges, u16* __restrict__ agg)
{
    int wid  = (blockIdx.x * 256 + threadIdx.x) >> 6;
    int lane = threadIdx.x & 63;
    int sl   = lane & 31;           // sublane: dim pair -> dims 2sl, 2sl+1
    int node = wid * 2 + (lane >> 5);
    if (node >= N_NODES) return;
    int b = rowptr[node];
    int e = rowptr[node + 1];
    float acc0 = 0.f, acc1 = 0.f;
    for (int base = b; base < e; base += 32) {
        int cnt = min(32, e - base);
        int idx = 0;
        float wv = 0.f;
        if (sl < cnt) {
            int2 p = edges[base + sl];   // per-half coalesced 256B segment
            idx = p.x;
            wv = __int_as_float(p.y);
        }
        int j = 0;
        for (; j + 8 <= cnt; j += 8) {
            int s0 = __shfl(idx, j + 0, 32), s1 = __shfl(idx, j + 1, 32);
            int s2 = __shfl(idx, j + 2, 32), s3 = __shfl(idx, j + 3, 32);
            int s4 = __shfl(idx, j + 4, 32), s5 = __shfl(idx, j + 5, 32);
            int s6 = __shfl(idx, j + 6, 32), s7 = __shfl(idx, j + 7, 32);
            float w0 = __shfl(wv, j + 0, 32), w1 = __shfl(wv, j + 1, 32);
            float w2 = __shfl(wv, j + 2, 32), w3 = __shfl(wv, j + 3, 32);
            float w4 = __shfl(wv, j + 4, 32), w5 = __shfl(wv, j + 5, 32);
            float w6 = __shfl(wv, j + 6, 32), w7 = __shfl(wv, j + 7, 32);
            unsigned int p0 = *(const unsigned int*)(h + ((size_t)s0 << 6) + sl * 2);
            unsigned int p1 = *(const unsigned int*)(h + ((size_t)s1 << 6) + sl * 2);
            unsigned int p2 = *(const unsigned int*)(h + ((size_t)s2 << 6) + sl * 2);
            unsigned int p3 = *(const unsigned int*)(h + ((size_t)s3 << 6) + sl * 2);
            unsigned int p4 = *(const unsigned int*)(h + ((size_t)s4 << 6) + sl * 2);
            unsigned int p5 = *(const unsigned int*)(h + ((size_t)s5 << 6) + sl * 2);
            unsigned int p6 = *(const unsigned int*)(h + ((size_t)s6 << 6) + sl * 2);
            unsigned int p7 = *(const unsigned int*)(h + ((size_t)s7 << 6) + sl * 2);
            acc0 += bf2f_lo(p0) * w0 + bf2f_lo(p1) * w1
                  + bf2f_lo(p2) * w2 + bf2f_lo(p3) * w3
                  + bf2f_lo(p4) * w4 + bf2f_lo(p5) * w5
                  + bf2f_lo(p6) * w6 + bf2f_lo(p7) * w7;
            acc1 += bf2f_hi(p0) * w0 + bf2f_hi(p1) * w1
                  + bf2f_hi(p2) * w2 + bf2f_hi(p3) * w3
                  + bf2f_hi(p4) * w4 + bf2f_hi(p5) * w5
                  + bf2f_hi(p6) * w6 + bf2f_hi(p7) * w7;
        }
        for (; j < cnt; ++j) {
            int s = __shfl(idx, j, 32);
            float w = __shfl(wv, j, 32);
            unsigned int pk = *(const unsigned int*)(h + ((size_t)s << 6) + sl * 2);
            acc0 += bf2f_lo(pk) * w;
            acc1 += bf2f_hi(pk) * w;
        }
    }
    unsigned int o = ((unsigned int)f2bf(acc1) << 16) | f2bf(acc0);
    *(unsigned int*)(agg + ((size_t)node << 6) + sl * 2) = o;
}

// =================== Dense update via MFMA (no LDS, no barrier) ==============
// Wave = 16 nodes x 64 out-dims = 4 n-tiles x 4 k-steps of 16x16x32 bf16.
// A-frag: lane holds AX[m=lane&15][k=quad*8+j] (doc-verified). B-frag:
// lane holds W2[k=quad*8+j][n=lane&15], read from transposed W2T[n][k].
// D: col(n)=lane&15, row(m)=quad*4+reg (doc-verified). In-place safe:
// wave reads/writes only its own 16 rows; stores data-depend on all loads.
__global__ __launch_bounds__(256) void update_mfma_kernel(
    const u16* __restrict__ hin, const u16* __restrict__ agg,
    const u16* __restrict__ W2T, const float* __restrict__ brel,
    u16* __restrict__ hout_bf, float* __restrict__ hout_f32, int relu)
{
    const int wave = threadIdx.x >> 6;
    const int lane = threadIdx.x & 63;
    const int nb16 = blockIdx.x * 64 + wave * 16;
    const int m = lane & 15;   // node-in-tile for A; out-dim-in-tile for B/D
    const int q = lane >> 4;   // quad

    int anode = nb16 + m;
    size_t rowa = (size_t)((anode < N_NODES) ? anode : 0) << 6;

    bf16x8 a[4];
    a[0] = *(const bf16x8*)(agg + rowa + q * 8);        // k  0..31
    a[1] = *(const bf16x8*)(agg + rowa + 32 + q * 8);   // k 32..63
    a[2] = *(const bf16x8*)(hin + rowa + q * 8);        // k 64..95
    a[3] = *(const bf16x8*)(hin + rowa + 32 + q * 8);   // k 96..127

    bf16x8 bfr[4][4];  // [ntile][kstep]
    #pragma unroll
    for (int nt = 0; nt < 4; ++nt)
        #pragma unroll
        for (int kk = 0; kk < 4; ++kk)
            bfr[nt][kk] = *(const bf16x8*)(W2T + (size_t)(nt * 16 + m) * 128
                                           + kk * 32 + q * 8);

    f32x4 acc[4];
    #pragma unroll
    for (int nt = 0; nt < 4; ++nt) {
        float bv = brel[nt * 16 + m];
        acc[nt] = (f32x4){bv, bv, bv, bv};
    }

    #pragma unroll
    for (int kk = 0; kk < 4; ++kk)
        #pragma unroll
        for (int nt = 0; nt < 4; ++nt)
            acc[nt] = __builtin_amdgcn_mfma_f32_16x16x32_bf16(
                a[kk], bfr[nt][kk], acc[nt], 0, 0, 0);

    #pragma unroll
    for (int nt = 0; nt < 4; ++nt)
        #pragma unroll
        for (int r = 0; r < 4; ++r) {
            int n2 = nb16 + q * 4 + r;           // node (row of D)
            if (n2 < N_NODES) {
                float v = acc[nt][r];
                if (relu) v = fmaxf(v, 0.f);
                int dim = nt * 16 + m;           // out dim (col of D)
                if (hout_f32) hout_f32[(size_t)n2 * 64 + dim] = v;
                else          hout_bf [(size_t)n2 * 64 + dim] = f2bf(v);
            }
        }
}

extern "C" void kernel_launch(void* const* d_in, const int* in_sizes, int n_in,
                              void* d_out, int out_size, void* d_ws, size_t ws_size,
                              hipStream_t stream)
{
    const float* x     = (const float*)d_in[0];
    const int*   ei    = (const int*)d_in[1];   // [2, E] int32
    const float* ew    = (const float*)d_in[2];
    const float* Wrel  = (const float*)d_in[3]; // [5, 64, 64]
    const float* brel  = (const float*)d_in[4]; // [5, 64]
    const float* Wroot = (const float*)d_in[5]; // [5, 64, 64]
    float* out = (float*)d_out;

    const int* src = ei;
    const int* dst = ei + N_EDGES;

    const size_t featb_bytes = (size_t)N_NODES * D * 2;  // 12.8 MB bf16
    char* ws = (char*)d_ws;
    size_t off = 0;
    u16*  hb     = (u16*)(ws + off);  off += featb_bytes;
    u16*  aggb   = (u16*)(ws + off);  off += featb_bytes;
    u16*  W2T    = (u16*)(ws + off);  off += (size_t)N_LAYERS * 64 * 128 * 2;
    int*  rowptr = (int*)(ws + off);  off += 400016;
    int*  fcur   = (int*)(ws + off);  off += NX * FB * 4;
    int*  fbase  = (int*)(ws + off);  off += (FB + 1) * 4 + 60;
    int2* edges  = (int2*)(ws + off); off += (size_t)N_EDGES * 8;

    // stag aliases hb+aggb (8000 cells * 320 * 8B = 20.48MB < 25.6MB): live
    // only bin -> sort, both complete (stream-ordered) before f2bf writes hb
    // / agg writes aggb.
    u64* stag = (u64*)ws;

    const int cblocks = (N_NODES * D / 4 + 255) / 256;
    const int wblocks = (N_LAYERS * 64 * 128 + 255) / 256;  // 160
    const int ablocks = ((N_NODES + 1) / 2 + 3) / 4; // 12500 (2 nodes/wave)
    const int ublocks = (N_NODES + 63) / 64;         // 1563

    // ---- CSR build (counting sort) + converts ----
    initcur_kernel<<<8, 1024, 0, stream>>>(fcur);
    bin_kernel<<<BIN_BLOCKS, BIN_THREADS, 0, stream>>>(src, dst, ew, fcur, stag);
    fscan_kernel<<<1, 1024, 0, stream>>>(fcur, fbase, rowptr);
    sort_kernel<<<FB, 256, 0, stream>>>(stag, fcur, fbase, rowptr, edges);
    f2bf_kernel<<<cblocks, 256, 0, stream>>>(x, hb);
    wprep_kernel<<<wblocks, 256, 0, stream>>>(Wrel, Wroot, W2T);

    // ---- 5 GraphConv layers (hb updated in place; wave-local rows) ----
    for (int layer = 0; layer < N_LAYERS; ++layer) {
        agg_kernel<<<ablocks, 256, 0, stream>>>(hb, rowptr, edges, aggb);
        int last = (layer == N_LAYERS - 1);
        update_mfma_kernel<<<ublocks, 256, 0, stream>>>(
            hb, aggb, W2T + (size_t)layer * 64 * 128,
            brel + (size_t)layer * D,
            last ? nullptr : hb, last ? out : nullptr,
            last ? 0 : 1);
    }
}